// Round 2
// baseline (569.161 us; speedup 1.0000x reference)
//
#include <hip/hip_runtime.h>
#include <math.h>

#define B_  64
#define S_  128
#define LW_ 20
#define CHAR_E_ 30
#define CHAR_C_ 30
#define WORD_E_ 300
#define H_  256
#define NC_ 25
#define F_  330
#define KP_ 352       // K padded to multiple of 32
#define G4_ 1024      // 4*H
#define NG_ 2048      // both directions' gates

typedef __attribute__((ext_vector_type(8))) short short8;
typedef __attribute__((ext_vector_type(4))) float floatx4;
typedef __attribute__((ext_vector_type(8))) int int8v;

__device__ __forceinline__ float sigmoidf_(float x){ return 1.0f/(1.0f+__expf(-x)); }
__device__ __forceinline__ float tanh_(float x){ return 1.0f - 2.0f/(1.0f+__expf(2.0f*x)); }

__device__ __forceinline__ unsigned int f2bf(float f){
    unsigned int u = __float_as_uint(f);
    u += 0x7FFFu + ((u>>16)&1u);
    return (u>>16) & 0xFFFFu;
}
__device__ __forceinline__ float bf2f(unsigned int v){ return __uint_as_float(v<<16); }

// async global->LDS, 16B per lane; LDS dest is wave-uniform base + lane*16
__device__ __forceinline__ void gload16(const void* g, void* l){
    __builtin_amdgcn_global_load_lds((const __attribute__((address_space(1))) unsigned int*)g,
                                     (__attribute__((address_space(3))) unsigned int*)l, 16, 0, 0);
}

// LDS-only barrier: does NOT drain vmcnt, so global prefetch loads stay in flight.
#define BAR_LDS() __asm__ volatile("s_waitcnt lgkmcnt(0)\n\ts_barrier" ::: "memory")

// ---------------- merged prep: charconv | wemb | pack | init ----------------
// grid = 1024 + 2432 + 2816 + 1 = 6273 blocks x 256
__global__ __launch_bounds__(256) void k_prep(const float* ct, const int* word,
        const float* cw, const float* cb, const float* wt, const int* sent,
        const float* wf, const float* wr, float* out,
        unsigned short* feat, unsigned short* wpack){
    __shared__ __align__(16) float x[8][32][20];
    int blk = blockIdx.x;
    int tid = threadIdx.x;
    if(blk < 1024){
        // -------- char conv + maxpool into feat cols [300,330) --------
        int tok0 = blk*8;
        for(int e = tid; e < 8*32*20; e += 256){
            int t  = e % 20;
            int ic = (e/20) & 31;
            int tl = e / 640;
            int id = word[(size_t)(tok0+tl)*LW_ + t];
            float v = 0.f;
            if(ic < CHAR_E_ && id != 0) v = ct[(size_t)id*CHAR_E_ + ic];
            x[tl][ic][t] = v;
        }
        __syncthreads();
        if(tid < 240){
            int tl = tid/30, oc = tid%30;
            float acc[22];
            #pragma unroll
            for(int q=0;q<22;q++) acc[q] = 0.f;
            for(int ic=0; ic<CHAR_E_; ic++){
                float w0 = cw[(oc*CHAR_E_+ic)*3+0];
                float w1 = cw[(oc*CHAR_E_+ic)*3+1];
                float w2 = cw[(oc*CHAR_E_+ic)*3+2];
                const float* xr = &x[tl][ic][0];
                #pragma unroll
                for(int t4=0;t4<5;t4++){
                    float4 v = ((const float4*)xr)[t4];
                    int t0 = t4*4;
                    acc[t0+2] += v.x*w0; acc[t0+1] += v.x*w1; acc[t0+0] += v.x*w2;
                    acc[t0+3] += v.y*w0; acc[t0+2] += v.y*w1; acc[t0+1] += v.y*w2;
                    acc[t0+4] += v.z*w0; acc[t0+3] += v.z*w1; acc[t0+2] += v.z*w2;
                    acc[t0+5] += v.w*w0; acc[t0+4] += v.w*w1; acc[t0+3] += v.w*w2;
                }
            }
            float m = -1e30f;
            #pragma unroll
            for(int t=0;t<20;t++){ float v = acc[t+1]; m = fmaxf(m, v); }
            m += cb[oc];
            feat[(size_t)(tok0+tl)*KP_ + WORD_E_ + oc] = (unsigned short)f2bf(m);
        }
    } else if(blk < 1024+2432){
        // -------- word embedding into feat cols [0,300), zeros [330,352) --------
        int idx = (blk-1024)*256 + tid;
        int n = idx / 76, e4 = idx % 76;
        if(e4 < 75){
            float4 v = ((const float4*)(wt + (size_t)sent[n]*WORD_E_))[e4];
            unsigned int lo = f2bf(v.x) | (f2bf(v.y)<<16);
            unsigned int hi = f2bf(v.z) | (f2bf(v.w)<<16);
            uint2 pr; pr.x = lo; pr.y = hi;
            *(uint2*)(feat + (size_t)n*KP_ + e4*4) = pr;
        } else {
            unsigned int* z = (unsigned int*)(feat + (size_t)n*KP_ + 330);
            #pragma unroll
            for(int q=0;q<11;q++) z[q] = 0;
        }
    } else if(blk < 6272){
        // -------- pack w_ih (f then r) into bf16 (2048 x 352) --------
        int i = (blk-3456)*256 + tid;
        int r = i / KP_, k = i % KP_;
        const float* src = (r < G4_) ? wf : wr;
        int rr = r & (G4_-1);
        wpack[i] = (k < F_) ? (unsigned short)f2bf(src[(size_t)rr*F_ + k]) : 0;
    } else {
        if(tid == 0) *out = 0.f;
    }
}

// ---------------- bf16 MFMA GEMM (m97 structure): gx = feat(8192x352) . wpack(2048x352)^T + bias ----------------
// 128x128 tile, 4 waves in 2x2, 4x4 16x16 frags per wave, global_load_lds(16B) staging, linear LDS.
// Output gxb is TOKEN-MAJOR: gxb[token*2048 + n], n = dir*1024 + grow.
__global__ __launch_bounds__(256) void k_gemm(const unsigned short* A, const unsigned short* Bw,
                                              const float* bf, const float* br, unsigned short* gxb){
    __shared__ __align__(16) unsigned short As[128*32];
    __shared__ __align__(16) unsigned short Bs[128*32];
    int m0 = blockIdx.x*128, n0 = blockIdx.y*128;
    int tid = threadIdx.x;
    int w = tid>>6, lane = tid&63, q = lane>>4, l16 = lane&15;
    int wr = w>>1, wc = w&1;
    // staging: wave w fills LDS bytes [w*2048, w*2048+2048) of each tile (2 calls of 1024B)
    int srow0 = w*32 + (lane>>2);          // call 0: rows w*32 .. w*32+15
    int scol  = (lane&3)*8;                // 8 bf16 = 16B per lane
    floatx4 acc[4][4];
    #pragma unroll
    for(int i=0;i<4;i++)
        #pragma unroll
        for(int j=0;j<4;j++) acc[i][j] = (floatx4){0.f,0.f,0.f,0.f};

    for(int k0=0; k0<KP_; k0+=32){
        __syncthreads();   // previous iteration's LDS reads complete (lgkm drained by syncthreads)
        gload16(A  + (size_t)(m0+srow0   )*KP_ + k0 + scol, (unsigned short*)As + w*1024      );
        gload16(A  + (size_t)(m0+srow0+16)*KP_ + k0 + scol, (unsigned short*)As + w*1024 + 512);
        gload16(Bw + (size_t)(n0+srow0   )*KP_ + k0 + scol, (unsigned short*)Bs + w*1024      );
        gload16(Bw + (size_t)(n0+srow0+16)*KP_ + k0 + scol, (unsigned short*)Bs + w*1024 + 512);
        __asm__ volatile("s_waitcnt vmcnt(0)" ::: "memory");
        __syncthreads();
        short8 a_[4], b_[4];
        #pragma unroll
        for(int i=0;i<4;i++) a_[i] = *(const short8*)&As[(wr*64 + i*16 + l16)*32 + q*8];
        #pragma unroll
        for(int j=0;j<4;j++) b_[j] = *(const short8*)&Bs[(wc*64 + j*16 + l16)*32 + q*8];
        #pragma unroll
        for(int i=0;i<4;i++)
            #pragma unroll
            for(int j=0;j<4;j++)
                acc[i][j] = __builtin_amdgcn_mfma_f32_16x16x32_bf16(a_[i], b_[j], acc[i][j], 0,0,0);
    }
    // epilogue: C[m][n] with m = m0+wr*64+i*16+q*4+r, n = n0+wc*64+j*16+l16
    #pragma unroll
    for(int j=0;j<4;j++){
        int n = n0 + wc*64 + j*16 + l16;
        int dirr = n >> 10, grow = n & 1023;
        float bias = dirr ? br[grow] : bf[grow];
        #pragma unroll
        for(int i=0;i<4;i++){
            int mb = m0 + wr*64 + i*16 + q*4;
            #pragma unroll
            for(int r=0;r<4;r++){
                gxb[(size_t)(mb+r)*NG_ + n] = (unsigned short)f2bf(acc[i][j][r] + bias);
            }
        }
    }
}

// ---------------- one LSTM step body (inlined) ----------------
__device__ __forceinline__ void lstm_step(
    const unsigned char* hbb, unsigned char* hwr_slot,
    float* wreg_lds, const int8v (*wreg)[2][2],
    int l16, int q, int cbl, int urel,
    unsigned int G0, unsigned int G1, unsigned int G2, unsigned int G3,
    float& cc, float* hseq_ptr, const float inv_sc)
{
    floatx4 a00={0.f,0.f,0.f,0.f}, a01=a00, a10=a00, a11=a00,
            a20=a00, a21=a00, a30=a00, a31=a00;
    #pragma unroll
    for(int ki=0; ki<2; ki++){
        int8v hb = *(const int8v*)&hbb[l16*272 + ki*128 + q*32];
        a00 = __builtin_amdgcn_mfma_scale_f32_16x16x128_f8f6f4(wreg[0][0][ki], hb, a00, 0,0,0,0x7F,0,0x7F);
        a01 = __builtin_amdgcn_mfma_scale_f32_16x16x128_f8f6f4(wreg[0][1][ki], hb, a01, 0,0,0,0x7F,0,0x7F);
        a10 = __builtin_amdgcn_mfma_scale_f32_16x16x128_f8f6f4(wreg[1][0][ki], hb, a10, 0,0,0,0x7F,0,0x7F);
        a11 = __builtin_amdgcn_mfma_scale_f32_16x16x128_f8f6f4(wreg[1][1][ki], hb, a11, 0,0,0,0x7F,0,0x7F);
        a20 = __builtin_amdgcn_mfma_scale_f32_16x16x128_f8f6f4(wreg[2][0][ki], hb, a20, 0,0,0,0x7F,0,0x7F);
        a21 = __builtin_amdgcn_mfma_scale_f32_16x16x128_f8f6f4(wreg[2][1][ki], hb, a21, 0,0,0,0x7F,0,0x7F);
        a30 = __builtin_amdgcn_mfma_scale_f32_16x16x128_f8f6f4(wreg[3][0][ki], hb, a30, 0,0,0,0x7F,0,0x7F);
        a31 = __builtin_amdgcn_mfma_scale_f32_16x16x128_f8f6f4(wreg[3][1][ki], hb, a31, 0,0,0,0x7F,0,0x7F);
    }
    // scatter to [g][batch(l16)][unit]: vectorized 16B LDS writes (2-way banked: free)
    if(l16 < 2){
        int base = l16*32 + q*4;
        *(floatx4*)&wreg_lds[0*64 + base     ] = a00;
        *(floatx4*)&wreg_lds[0*64 + base + 16] = a01;
        *(floatx4*)&wreg_lds[1*64 + base     ] = a10;
        *(floatx4*)&wreg_lds[1*64 + base + 16] = a11;
        *(floatx4*)&wreg_lds[2*64 + base     ] = a20;
        *(floatx4*)&wreg_lds[2*64 + base + 16] = a21;
        *(floatx4*)&wreg_lds[3*64 + base     ] = a30;
        *(floatx4*)&wreg_lds[3*64 + base + 16] = a31;
    }
    // same-wave ds write->read: DS pipe is in-order per wave; no barrier needed
    int cidx = cbl*32 + urel;
    float iv = wreg_lds[0*64 + cidx]*inv_sc + bf2f(G0);
    float fv = wreg_lds[1*64 + cidx]*inv_sc + bf2f(G1);
    float gv = wreg_lds[2*64 + cidx]*inv_sc + bf2f(G2);
    float ov = wreg_lds[3*64 + cidx]*inv_sc + bf2f(G3);
    float cn = sigmoidf_(fv)*cc + sigmoidf_(iv)*tanh_(gv);
    cc = cn;
    float hv = sigmoidf_(ov)*tanh_(cn);
    *hseq_ptr = hv;
    unsigned int hp8 = __builtin_amdgcn_cvt_pk_fp8_f32(hv*16.f, hv*16.f, 0u, false);
    *hwr_slot = (unsigned char)(hp8 & 0xFF);
    BAR_LDS();   // h(t) published; everyone past reads of the read-buffer
}

// ---------------- persistent biLSTM: 64 blocks x 512 threads (8 waves) ----------------
// block = (dir, 2-batch group). K=128 MX fp8 A-frags = 128 VGPR/lane. t-loop unrolled
// x2 with register rotation (no gc=gn copies -> gx prefetch survives the backedge).
// One lgkm-only barrier per step; gate xfer is intra-wave via per-wave LDS region.
__global__ __launch_bounds__(512,2) void k_lstm_all(const float* whhf, const float* whhr,
        const unsigned short* gxb, float* hseq)
{
    int bid = blockIdx.x;        // 0..63
    int dir = bid >> 5;
    int bg  = bid & 31;          // 2 batches: bg*2, bg*2+1
    int tid = threadIdx.x;
    int w    = tid >> 6;         // wave 0..7: units w*32..w*32+31
    int lane = tid & 63;
    int q    = lane >> 4;
    int l16  = lane & 15;

    __shared__ __align__(16) unsigned char hlds[2][16*272];   // [buf][batchrow][unit] fp8 (rows 2..15 = 0)
    __shared__ __align__(16) float wregion[8*256];            // per-wave gate xfer (8KB)

    const float* whh = dir ? whhr : whhf;

    // one-time: pack weight slice as K=128 fp8 A-fragments.
    // row = g*256 + w*32 + j*16 + l16 ; k = ki*128 + q*32 + byte (matches B-load)
    int8v wreg[4][2][2];   // [gate][j][ki] -> 128 VGPRs
    #pragma unroll
    for(int g=0; g<4; g++){
        #pragma unroll
        for(int j=0; j<2; j++){
            const float* rp = whh + (size_t)(g*H_ + w*32 + j*16 + l16)*H_;
            #pragma unroll
            for(int ki=0; ki<2; ki++){
                const float* p = rp + ki*128 + q*32;
                int8v acc;
                #pragma unroll
                for(int wd=0; wd<8; wd++){
                    unsigned int d = 0;
                    d = __builtin_amdgcn_cvt_pk_fp8_f32(p[wd*4+0]*64.f, p[wd*4+1]*64.f, d, false);
                    d = __builtin_amdgcn_cvt_pk_fp8_f32(p[wd*4+2]*64.f, p[wd*4+3]*64.f, d, true);
                    acc[wd] = (int)d;
                }
                wreg[g][j][ki] = acc;
            }
        }
    }

    for(int i = tid; i < 2*16*272/4; i += 512) ((unsigned int*)hlds)[i] = 0;
    __syncthreads();

    // cell role (intra-wave): lane = cbl*32 + urel; unit cu = w*32+urel, batch bg*2+cbl
    int urel = lane & 31;
    int cbl  = lane >> 5;        // 0..1
    int cu   = w*32 + urel;
    int b_glob = bg*2 + cbl;
    const float inv_sc = 1.0f/1024.f;   // w x64, h x16

    float cc = 0.f;
    // token-major gxb: gxb[token*NG + dir*G4 + grow], token = b*S + s
    const unsigned short* gbase = gxb + (size_t)b_glob*S_*NG_ + (size_t)dir*G4_ + cu;
    float* hseq_base = hseq + ((size_t)dir*S_*B_ + b_glob)*H_ + cu;
    unsigned char* hw0 = &hlds[0][cbl*272 + cu];
    unsigned char* hw1 = &hlds[1][cbl*272 + cu];
    float* wreg_lds = &wregion[w*256];

    unsigned int p0,p1,p2,p3, q0,q1,q2,q3;
    {
        const unsigned short* gp = gbase + (size_t)(dir ? (S_-1) : 0)*NG_;
        p0 = gp[0]; p1 = gp[256]; p2 = gp[512]; p3 = gp[768];
    }

    for(int t=0; t<S_; t+=2){
        int sA = dir ? (S_-1-t) : t;
        int sB = dir ? (S_-2-t) : (t+1);
        int sC = (t+2 < S_) ? (dir ? (S_-3-t) : (t+2)) : sB;   // dummy-safe

        // prefetch step t+1's gates (consumed after step A's MFMA block)
        {
            const unsigned short* gp = gbase + (size_t)sB*NG_;
            q0 = gp[0]; q1 = gp[256]; q2 = gp[512]; q3 = gp[768];
        }
        // step A: read buf0, write buf1
        lstm_step(&hlds[0][0], hw1, wreg_lds, wreg, l16, q, cbl, urel,
                  p0,p1,p2,p3, cc, hseq_base + (size_t)sA*B_*H_, inv_sc);

        // prefetch step t+2's gates
        {
            const unsigned short* gp = gbase + (size_t)sC*NG_;
            p0 = gp[0]; p1 = gp[256]; p2 = gp[512]; p3 = gp[768];
        }
        // step B: read buf1, write buf0
        lstm_step(&hlds[1][0], hw0, wreg_lds, wreg, l16, q, cbl, urel,
                  q0,q1,q2,q3, cc, hseq_base + (size_t)sB*B_*H_, inv_sc);
    }
}

// ---------------- emissions: block = 8 (s,b) pairs, h staged in LDS ----------------
__global__ __launch_bounds__(256) void k_em(const float* hseq, const float* lw, const float* lb, float* em){
    __shared__ __align__(16) float hb[8][516];   // +4 pad
    int sb0 = blockIdx.x*8;
    int tid = threadIdx.x;
    for(int i = tid; i < 1024; i += 256){
        int p = i >> 7, r = i & 127;
        int sb = sb0 + p, s = sb >> 6, b = sb & 63;
        const float* src = (r < 64) ? (hseq + (((size_t)0*S_+s)*B_+b)*H_ + r*4)
                                    : (hseq + (((size_t)1*S_+s)*B_+b)*H_ + (r-64)*4);
        *(float4*)&hb[p][r*4] = *(const float4*)src;
    }
    __syncthreads();
    if(tid < 200){
        int p = tid / 25, nc = tid % 25;
        const float4* wv = (const float4*)(lw + (size_t)nc*2*H_);
        const float4* hv = (const float4*)&hb[p][0];
        float acc = lb[nc];
        #pragma unroll 16
        for(int k=0;k<128;k++){ float4 a=hv[k], ww=wv[k]; acc += a.x*ww.x + a.y*ww.y + a.z*ww.z + a.w*ww.w; }
        em[(size_t)(sb0+p)*NC_ + nc] = acc;
    }
}

// ---------------- CRF NLL: one block = one WAVE (64 threads) per batch, no barriers ----------------
__global__ void k_crf(const float* em, const int* tag, const void* mask,
                      const float* st, const float* et, const float* tr, float* out){
    __shared__ float trs[NC_*NC_];
    int b = blockIdx.x, tid = threadIdx.x;
    for(int i=tid;i<NC_*NC_;i+=64) trs[i]=tr[i];
    unsigned int first = *(const unsigned int*)mask;
    int ml;  // 0=int32, 1=uint8, 2=float32
    if(first == 1u) ml = 0;
    else if(first == 0x3F800000u) ml = 2;
    else ml = 1;
    __syncthreads();

    // gold path score
    float part = 0.f; int cnt = 0;
    for(int s = tid; s < S_; s += 64){
        float mkv;
        {
            int off = b*S_ + s;
            if(ml==0)      mkv = ((const int*)mask)[off] ? 1.f : 0.f;
            else if(ml==1) mkv = ((const unsigned char*)mask)[off] ? 1.f : 0.f;
            else           mkv = ((const float*)mask)[off];
        }
        cnt += (mkv != 0.f) ? 1 : 0;
        if(s == 0){
            int t0 = tag[b*S_];
            part += st[t0] + em[((size_t)0*B_ + b)*NC_ + t0];
        } else {
            int tp = tag[b*S_ + s-1], tc = tag[b*S_ + s];
            part += mkv * (trs[tp*NC_ + tc] + em[((size_t)s*B_ + b)*NC_ + tc]);
        }
    }
    for(int o=32;o>0;o>>=1){ part += __shfl_down(part, o); cnt += __shfl_down(cnt, o); }
    float score = 0.f;
    int len = __shfl(cnt, 0);
    float score0 = __shfl(part, 0);
    if(tid == 0) score = score0 + et[ tag[b*S_ + len-1] ];

    // E columns in registers
    float Ecol[NC_];
    if(tid < NC_){
        #pragma unroll
        for(int i=0;i<NC_;i++) Ecol[i] = __expf(trs[i*NC_+tid]);
    } else {
        #pragma unroll
        for(int i=0;i<NC_;i++) Ecol[i] = 0.f;
    }

    float alpha = (tid < NC_) ? (st[tid] + em[((size_t)0*B_ + b)*NC_ + tid]) : -1e30f;
    float em_n = (tid < NC_) ? em[((size_t)1*B_ + b)*NC_ + tid] : 0.f;

    for(int s=1;s<S_;s++){
        float em_c = em_n;
        if(s+1 < S_) em_n = (tid < NC_) ? em[((size_t)(s+1)*B_ + b)*NC_ + tid] : 0.f;
        float mkv;
        {
            int off = b*S_ + s;
            if(ml==0)      mkv = ((const int*)mask)[off] ? 1.f : 0.f;
            else if(ml==1) mkv = ((const unsigned char*)mask)[off] ? 1.f : 0.f;
            else           mkv = ((const float*)mask)[off];
        }
        // max over the 25 live lanes: lanes 25..63 hold -1e30, so o=16 suffices
        float v = alpha;
        #pragma unroll
        for(int o=16;o>0;o>>=1) v = fmaxf(v, __shfl_down(v, o));
        float m = __shfl(v, 0);
        float a = (tid < NC_) ? __expf(alpha - m) : 0.f;
        float S0 = 0.f, S1 = 0.f;
        #pragma unroll
        for(int i=0;i<24;i+=2){ S0 += __shfl(a, i) * Ecol[i]; S1 += __shfl(a, i+1) * Ecol[i+1]; }
        S0 += __shfl(a, 24) * Ecol[24];
        float nxt = m + __logf(S0 + S1) + em_c;
        if(tid < NC_ && mkv != 0.f) alpha = nxt;
    }

    float v = (tid < NC_) ? (alpha + et[tid]) : -1e30f;
    float m2 = v;
    #pragma unroll
    for(int o=16;o>0;o>>=1) m2 = fmaxf(m2, __shfl_down(m2, o));
    m2 = __shfl(m2, 0);
    float e = (tid < NC_) ? __expf(v - m2) : 0.f;
    #pragma unroll
    for(int o=16;o>0;o>>=1) e += __shfl_down(e, o);
    if(tid == 0){
        float logZ = m2 + __logf(e);
        atomicAdd(out, logZ - score);
    }
}

extern "C" void kernel_launch(void* const* d_in, const int* in_sizes, int n_in,
                              void* d_out, int out_size, void* d_ws, size_t ws_size,
                              hipStream_t stream) {
    const float* word_table = (const float*)d_in[0];
    const float* char_table = (const float*)d_in[1];
    const float* conv_w     = (const float*)d_in[2];
    const float* conv_b     = (const float*)d_in[3];
    const float* w_ih_f     = (const float*)d_in[4];
    const float* w_hh_f     = (const float*)d_in[5];
    const float* b_f        = (const float*)d_in[6];
    const float* w_ih_r     = (const float*)d_in[7];
    const float* w_hh_r     = (const float*)d_in[8];
    const float* b_r        = (const float*)d_in[9];
    const float* lin_w      = (const float*)d_in[10];
    const float* lin_b      = (const float*)d_in[11];
    const float* start_t    = (const float*)d_in[12];
    const float* end_t      = (const float*)d_in[13];
    const float* trans      = (const float*)d_in[14];
    const int*   sent       = (const int*)d_in[15];
    const int*   word       = (const int*)d_in[16];
    const int*   tag        = (const int*)d_in[17];
    const void*  mask       = d_in[18];
    float* out = (float*)d_out;

    char* ws = (char*)d_ws;
    unsigned short* feat  = (unsigned short*)ws;                 // 8192*352*2   = 5,767,168 B
    unsigned short* wpack = (unsigned short*)(ws + 5767168);     // 2048*352*2   = 1,441,792 B
    unsigned short* gxb   = (unsigned short*)(ws + 5767168 + 1441792);           // 33,554,432 B (token-major)
    float* hseq = (float*)(ws + 5767168 + 1441792 + 33554432);   // 16,777,216 B
    float* em   = (float*)(ws + 5767168 + 1441792 + 33554432 + 16777216);        // 204,800 f

    k_prep<<<dim3(6273), 256, 0, stream>>>(char_table, word, conv_w, conv_b,
                                           word_table, sent, w_ih_f, w_ih_r, out, feat, wpack);
    k_gemm<<<dim3(B_*S_/128, NG_/128), 256, 0, stream>>>(feat, wpack, b_f, b_r, gxb);
    k_lstm_all<<<dim3(64), 512, 0, stream>>>(w_hh_f, w_hh_r, gxb, hseq);
    k_em<<<dim3(S_*B_/8), 256, 0, stream>>>(hseq, lin_w, lin_b, em);
    k_crf<<<dim3(B_), 64, 0, stream>>>(em, tag, mask, start_t, end_t, trans, out);
}